// Round 16
// baseline (438.074 us; speedup 1.0000x reference)
//
#include <hip/hip_runtime.h>
#include <hip/hip_bf16.h>
#include <math.h>

// ---------- types ----------
typedef short short8 __attribute__((ext_vector_type(8)));
typedef float f32x4 __attribute__((ext_vector_type(4)));

#define MFMA16(a, b, c) __builtin_amdgcn_mfma_f32_16x16x32_bf16((a), (b), (c), 0, 0, 0)
#define SM2 0.18033688f   // 0.125 * log2(e): QK^T softmax done in exp2 domain

// raw barrier + compiler fence (counted-vmcnt pipeline: loads stay in flight across it)
#define BARRIER() { __builtin_amdgcn_sched_barrier(0); \
                    asm volatile("s_barrier" ::: "memory"); \
                    __builtin_amdgcn_sched_barrier(0); }
#define WAITVM(n) asm volatile("s_waitcnt vmcnt(" #n ")" ::: "memory")

__device__ __forceinline__ unsigned short f2bf(float f) {
  unsigned u = __builtin_bit_cast(unsigned, f);
  u += 0x7FFFu + ((u >> 16) & 1u);   // RNE
  return (unsigned short)(u >> 16);
}
__device__ __forceinline__ float b2f(unsigned short h) {
  return __builtin_bit_cast(float, (unsigned)h << 16);
}
__device__ __forceinline__ unsigned cvtpk(float lo, float hi) {
  unsigned r;
  asm("v_cvt_pk_bf16_f32 %0, %1, %2" : "=v"(r) : "v"(lo), "v"(hi));
  return r;
}
__device__ __forceinline__ float vexp2(float x) {   // single-inst 2^x (inputs bounded)
  float r;
  asm("v_exp_f32 %0, %1" : "=v"(r) : "v"(x));
  return r;
}
// async global->LDS, 16B/lane; LDS dest = wave-uniform base (+ lane*16 by HW)
__device__ __forceinline__ void gload16(const void* g, void* l) {
  __builtin_amdgcn_global_load_lds((const __attribute__((address_space(1))) unsigned*)g,
                                   (__attribute__((address_space(3))) unsigned*)l, 16, 0, 0);
}

// ---------- fused cast + pool: x fp32 -> xbf bf16 (all rows) + pr bf16 (pooled) ----------
__global__ __launch_bounds__(256) void castpool(const float* __restrict__ x,
                                                unsigned short* __restrict__ xbf,
                                                unsigned short* __restrict__ pr) {
  long bi = blockIdx.x;                 // 0..12799
  const float* src = x + bi * 2560;
  unsigned short* dst = xbf + bi * 2560;
  int c = threadIdx.x * 2;
  float ax = 0.f, ay = 0.f;
#pragma unroll
  for (int w = 0; w < 5; ++w) {
    float2 v = *(const float2*)(src + w * 512 + c);
    ax += v.x; ay += v.y;
    unsigned o = (unsigned)f2bf(v.x) | ((unsigned)f2bf(v.y) << 16);
    *(unsigned*)(dst + w * 512 + c) = o;
  }
  unsigned o = (unsigned)f2bf(ax * 0.2f) | ((unsigned)f2bf(ay * 0.2f) << 16);
  *(unsigned*)(pr + bi * 512 + c) = o;
}

// merged transpose of the 5 weight matrices [512,N] fp32 -> [N,512] bf16 (contiguous dst)
__global__ __launch_bounds__(256) void wtrans5(const float* __restrict__ w0,
                                               const float* __restrict__ w1,
                                               const float* __restrict__ w2,
                                               const float* __restrict__ w3,
                                               const float* __restrict__ w4,
                                               unsigned short* __restrict__ dst) {
  int seg = blockIdx.y;
  const float* src; int N; long doff;
  switch (seg) {
    case 0:  src = w0; N = 768; doff = 0;       break;   // gqkv -> wtg
    case 1:  src = w1; N = 256; doff = 393216;  break;   // pq   -> wtq
    case 2:  src = w2; N = 512; doff = 524288;  break;   // pkv  -> wtkv
    case 3:  src = w3; N = 512; doff = 786432;  break;   // conv -> wtc
    default: src = w4; N = 512; doff = 1048576; break;   // proj -> wtp
  }
  int idx = blockIdx.x * 256 + threadIdx.x;
  if (idx < 512 * N) {
    int k = idx / N, n = idx - k * N;
    dst[doff + (long)n * 512 + k] = f2bf(src[idx]);
  }
}

// LayerNorm (eps 1e-5, biased var) + erf-GELU ; fp32 [rows,512] -> bf16
__global__ __launch_bounds__(256) void ln_gelu(const float* __restrict__ in,
                                               const float* __restrict__ g,
                                               const float* __restrict__ be,
                                               unsigned short* __restrict__ out) {
  long row = blockIdx.x;
  const float* src = in + row * 512;
  int tid = threadIdx.x;
  float2 v = *(const float2*)(src + tid * 2);
  float s = v.x + v.y, sq = v.x * v.x + v.y * v.y;
#pragma unroll
  for (int m = 1; m < 64; m <<= 1) {
    s  += __shfl_xor(s, m);
    sq += __shfl_xor(sq, m);
  }
  __shared__ float ss[4], ssq[4];
  int wv = tid >> 6;
  if ((tid & 63) == 0) { ss[wv] = s; ssq[wv] = sq; }
  __syncthreads();
  s  = ss[0] + ss[1] + ss[2] + ss[3];
  sq = ssq[0] + ssq[1] + ssq[2] + ssq[3];
  float mu = s * (1.0f / 512.0f);
  float var = sq * (1.0f / 512.0f) - mu * mu;
  float rs = rsqrtf(var + 1e-5f);
  int c = tid * 2;
#pragma unroll
  for (int e = 0; e < 2; ++e) {
    float xv = (e == 0 ? v.x : v.y);
    float y = (xv - mu) * rs * g[c + e] + be[c + e];
    float ge = 0.5f * y * (1.0f + erff(y * 0.70710678118654752f));
    out[row * 512 + c + e] = f2bf(ge);
  }
}

// ---------- V transpose: src [seq][800][64] -> dst [seq][64][800] ----------
__global__ __launch_bounds__(256) void vtrans(const unsigned short* __restrict__ src,
                                              unsigned short* __restrict__ dst) {
  __shared__ unsigned short tile[64][64];
  int jt = blockIdx.x, s = blockIdx.y;
  int tid = threadIdx.x;
#pragma unroll
  for (int p = 0; p < 2; ++p) {
    int idx = p * 256 + tid;
    int j = idx >> 3, d8 = (idx & 7) * 8;
    int jg = min(jt * 64 + j, 799);
    short8 v = *(const short8*)(src + ((long)s * 800 + jg) * 64 + d8);
    *(short8*)&tile[j][d8] = v;
  }
  __syncthreads();
  int d = tid >> 2, jseg = (tid & 3) * 16;
  if (jt * 64 + jseg < 800) {
    short8 h0, h1;
#pragma unroll
    for (int i = 0; i < 8; ++i) { h0[i] = (short)tile[jseg + i][d]; h1[i] = (short)tile[jseg + 8 + i][d]; }
    unsigned short* o = dst + ((long)s * 64 + d) * 800 + jt * 64 + jseg;
    *(short8*)o = h0;
    *(short8*)(o + 8) = h1;
  }
}

// ---------- small GEMM (pool branch): 128x128 tile, 4 waves, BK=32 ----------
// gmode 1: fp32 out0 [M][N];  gmode 3: kv-split gathered K/V [64][800][64]
__global__ __launch_bounds__(256) void gemm_bf16(const unsigned short* __restrict__ A,
                                                 const unsigned short* __restrict__ Bt,
                                                 const float* __restrict__ bias,
                                                 void* __restrict__ out0, void* __restrict__ out1,
                                                 int M, int N, int K, int gmode) {
  __shared__ unsigned short lA[2][128 * 32];
  __shared__ unsigned short lB[2][128 * 32];
  const int tid = threadIdx.x;
  const int lane = tid & 63, wv = tid >> 6;
  const int wr = wv >> 1, wc = wv & 1;
  const int l15 = lane & 15, lg = lane >> 4;

  const int nwg = gridDim.x * gridDim.y;
  const int bid = blockIdx.y * gridDim.x + blockIdx.x;
  const int w = (bid & 7) * (nwg >> 3) + (bid >> 3);
  const int m0 = (w / gridDim.x) * 128, n0 = (w % gridDim.x) * 128;

  const int r0  = tid >> 2;
  const int sw0 = ((tid & 3) * 16) ^ ((r0 & 3) << 4);
  const unsigned short* As0 = A  + (size_t)(m0 + r0)      * K + (sw0 >> 1);
  const unsigned short* As1 = A  + (size_t)(m0 + 64 + r0) * K + (sw0 >> 1);
  const unsigned short* Bs0 = Bt + (size_t)(n0 + r0)      * K + (sw0 >> 1);
  const unsigned short* Bs1 = Bt + (size_t)(n0 + 64 + r0) * K + (sw0 >> 1);

  f32x4 acc[4][4] = {};

#define GSTAGE(buf, k0)                                   \
  {                                                       \
    gload16(As0 + (k0), &lA[buf][wv * 512]);              \
    gload16(As1 + (k0), &lA[buf][2048 + wv * 512]);       \
    gload16(Bs0 + (k0), &lB[buf][wv * 512]);              \
    gload16(Bs1 + (k0), &lB[buf][2048 + wv * 512]);       \
  }

  const int nt = K >> 5;
  GSTAGE(0, 0);
  if (nt > 1) GSTAGE(1, 32);
  for (int t = 0; t < nt; ++t) {
    if (t + 1 < nt) { WAITVM(4); } else { WAITVM(0); }
    BARRIER();
    short8 af[4], bfr[4];
#pragma unroll
    for (int s2 = 0; s2 < 4; ++s2) {
      int ra = wr * 64 + s2 * 16 + l15;
      int rb = wc * 64 + s2 * 16 + l15;
      af[s2]  = *(const short8*)((char*)lA[t & 1] + ra * 64 + ((lg * 16) ^ ((ra & 3) << 4)));
      bfr[s2] = *(const short8*)((char*)lB[t & 1] + rb * 64 + ((lg * 16) ^ ((rb & 3) << 4)));
    }
#pragma unroll
    for (int i = 0; i < 4; ++i)
#pragma unroll
      for (int j = 0; j < 4; ++j)
        acc[i][j] = MFMA16(af[i], bfr[j], acc[i][j]);
    BARRIER();
    if (t + 2 < nt) GSTAGE(t & 1, (t + 2) * 32);
  }
#undef GSTAGE

#pragma unroll
  for (int i = 0; i < 4; ++i) {
#pragma unroll
    for (int r = 0; r < 4; ++r) {
      int row = m0 + wr * 64 + i * 16 + lg * 4 + r;
      long rg = 0;
      if (gmode == 3) {
        int b = row / 800, jj = row - b * 800;
        rg = (long)b * 204800 + (long)jj * 64;
      }
#pragma unroll
      for (int j = 0; j < 4; ++j) {
        int col = n0 + wc * 64 + j * 16 + l15;
        float vv = acc[i][j][r] + bias[col];
        if (gmode == 1) {
          ((float*)out0)[(size_t)row * N + col] = vv;
        } else {  // gmode 3
          int hh = (col >> 6) & 3, d = col & 63;
          unsigned short* dst = (col < 256) ? (unsigned short*)out0 : (unsigned short*)out1;
          dst[rg + hh * 51200 + d] = f2bf(vv);
        }
      }
    }
  }
}

// ---------- big GEMM: 256x256 tile, 8 waves (2Mx4N), wave-tile 128x64, BK=64 ----------
// 4-phase-per-K-tile schedule; coalesced LDS epilogue (R11, proven).
__global__ __launch_bounds__(512, 2) void gemm256(const unsigned short* __restrict__ A,
                                                  const unsigned short* __restrict__ Bt,
                                                  const float* __restrict__ bias,
                                                  const float* __restrict__ bias2,
                                                  void* __restrict__ out0, void* __restrict__ out1,
                                                  void* __restrict__ out2, void* __restrict__ out3,
                                                  int M, int N, int K, int gmode) {
  __shared__ char lds[131072];                 // lA[buf]=lds+buf*32768; lB[buf]=lds+65536+buf*32768
  const int tid = threadIdx.x;
  const int lane = tid & 63, wv = tid >> 6;    // 8 waves
  const int wr = wv >> 2, wc = wv & 3;         // 2M x 4N
  const int l15 = lane & 15, lg = lane >> 4;

  // bijective XCD swizzle (m204)
  const int nwg = gridDim.x * gridDim.y;
  const int bid = blockIdx.y * gridDim.x + blockIdx.x;
  const int q = nwg >> 3, r8 = nwg & 7;
  const int xcd = bid & 7, idx = bid >> 3;
  const int w = (xcd < r8 ? xcd * (q + 1) : r8 * (q + 1) + (xcd - r8) * q) + idx;
  const int m0 = (w / gridDim.x) * 256, n0 = (w % gridDim.x) * 256;

  const int srow = tid >> 3;                                        // 0..63
  const int scol = ((((lane & 7) ^ (lane >> 3)) << 4)) >> 1;        // element offset
  const unsigned short* Ag[4];
  const unsigned short* Bg[4];
#pragma unroll
  for (int g = 0; g < 4; ++g) {
    Ag[g] = A  + (size_t)(m0 + g * 64 + srow) * K + scol;
    Bg[g] = Bt + (size_t)(n0 + g * 64 + srow) * K + scol;
  }

  f32x4 acc[8][4] = {};

#define GSTAGE2(buf, k0)                                                    \
  {                                                                         \
    _Pragma("unroll")                                                       \
    for (int g = 0; g < 4; ++g)                                             \
      gload16(Ag[g] + (k0), lds + (buf) * 32768 + g * 8192 + wv * 1024);    \
    _Pragma("unroll")                                                       \
    for (int g = 0; g < 4; ++g)                                             \
      gload16(Bg[g] + (k0), lds + 65536 + (buf) * 32768 + g * 8192 + wv * 1024); \
  }
#define RDA4(ibase, kk)                                             \
  _Pragma("unroll")                                                 \
  for (int i = 0; i < 4; ++i) {                                     \
    int ra = wr * 128 + ((ibase) + i) * 16 + l15;                   \
    af[i] = *(const short8*)(bufA + ra * 128 +                      \
             (((kk) * 64 + lg * 16) ^ ((ra & 7) << 4)));            \
  }
#define RDB4(kk)                                                    \
  _Pragma("unroll")                                                 \
  for (int j = 0; j < 4; ++j) {                                     \
    int rb = wc * 64 + j * 16 + l15;                                \
    bf[j] = *(const short8*)(bufB + rb * 128 +                      \
             (((kk) * 64 + lg * 16) ^ ((rb & 7) << 4)));            \
  }
#define PH_MFMA(ibase)                                              \
  __builtin_amdgcn_s_setprio(1);                                    \
  _Pragma("unroll")                                                 \
  for (int i = 0; i < 4; ++i)                                       \
    _Pragma("unroll")                                               \
    for (int j = 0; j < 4; ++j)                                     \
      acc[(ibase) + i][j] = MFMA16(af[i], bf[j], acc[(ibase) + i][j]); \
  __builtin_amdgcn_s_setprio(0);

  const int nt = K >> 6;                       // BK=64
  GSTAGE2(0, 0);
  if (nt > 1) GSTAGE2(1, 64);
  for (int t = 0; t < nt; ++t) {
    if (t + 1 < nt) { WAITVM(8); } else { WAITVM(0); }
    BARRIER();
    const char* bufA = lds + (t & 1) * 32768;
    const char* bufB = lds + 65536 + (t & 1) * 32768;
    short8 af[4], bf[4];
    RDA4(0, 0); RDB4(0);
    BARRIER();
    PH_MFMA(0);
    BARRIER();
    RDA4(4, 0);
    BARRIER();
    PH_MFMA(4);
    BARRIER();
    RDA4(0, 1); RDB4(1);
    BARRIER();
    PH_MFMA(0);
    BARRIER();
    RDA4(4, 1);
    BARRIER();
    PH_MFMA(4);
    BARRIER();
    if (t + 2 < nt) GSTAGE2(t & 1, (t + 2) * 64);
  }
#undef GSTAGE2
#undef RDA4
#undef RDB4
#undef PH_MFMA

  // ---- coalesced epilogue via LDS (8 slices of [32 rows][256 cols]) ----
  float bb[4];
#pragma unroll
  for (int j = 0; j < 4; ++j) {
    int col = n0 + wc * 64 + j * 16 + l15;
    bb[j] = (gmode == 2 && col >= 768) ? bias2[col - 768] : bias[col];
  }
  const float qsc = (gmode == 2 && (n0 == 0 || n0 == 768)) ? SM2 : 1.0f;
  const int lwr = wr * 16 + lg * 4;
  const int lcol = wc * 64 + l15;
  const int lr_t = tid >> 4;
  const int c16 = (tid & 15) * 16;
  const int wrg = lr_t >> 4, rl = lr_t & 15;

  if (gmode == 1) {
    float* ls4 = (float*)lds;                  // [32][260] padded
#pragma unroll
    for (int i = 0; i < 8; ++i) {
      __syncthreads();
#pragma unroll
      for (int j = 0; j < 4; ++j)
#pragma unroll
        for (int rr = 0; rr < 4; ++rr)
          ls4[(lwr + rr) * 260 + lcol + j * 16] = acc[i][j][rr] + bb[j];
      __syncthreads();
      int gr = m0 + wrg * 128 + i * 16 + rl;
      float* dst = (float*)out0 + (size_t)gr * N + n0 + c16;
      const float* src = &ls4[lr_t * 260 + c16];
#pragma unroll
      for (int e = 0; e < 4; ++e)
        *(float4*)(dst + e * 4) = *(const float4*)(src + e * 4);
    }
  } else {  // gmode 2: merged qkv+poolq, bf16 gathered outputs
    unsigned short* ls2 = (unsigned short*)lds; // [32][264] padded
#pragma unroll
    for (int i = 0; i < 8; ++i) {
      __syncthreads();
#pragma unroll
      for (int j = 0; j < 4; ++j)
#pragma unroll
        for (int rr = 0; rr < 4; ++rr)
          ls2[(lwr + rr) * 264 + lcol + j * 16] = f2bf((acc[i][j][rr] + bb[j]) * qsc);
      __syncthreads();
      int gr = m0 + wrg * 128 + i * 16 + rl;
      unsigned short* dst;
      if (n0 == 768) {                         // pool Q: [row][256]
        dst = (unsigned short*)out3 + (size_t)gr * 256 + c16;
      } else {                                 // grid Q/K/V gathered [320][800][64]
        int b = gr / 4000, l = gr - b * 4000;
        int jj = l / 5, ww = l - jj * 5;
        long rg = (long)(b * 5 + ww) * 204800 + (long)jj * 64;
        unsigned short* base = (n0 == 0) ? (unsigned short*)out0
                             : (n0 == 256) ? (unsigned short*)out1 : (unsigned short*)out2;
        dst = base + rg + (c16 >> 6) * 51200 + (c16 & 63);
      }
      const unsigned short* src = &ls2[lr_t * 264 + c16];
      *(uint4*)dst = *(const uint4*)src;
      *(uint4*)(dst + 8) = *(const uint4*)(src + 8);
    }
  }
}

// ---------- flash attention v9: triple-buffered K/V, ONE barrier per tile ----------
// grid: 2240 grid-attn blocks then 2048 pool blocks. 4288 total, 8 waves, QBLK=128.
// Per tile: WAITVM(2) (own t-loads) -> BARRIER (all waves' t-loads done; buf (t-1)%3 free)
// -> FSTAGE((t+2)%3) early -> FTILE(t%3). 13 barriers/block (was 26).
__global__ __launch_bounds__(512) void flash_v9(const unsigned short* __restrict__ qg,
                                                const unsigned short* __restrict__ kg,
                                                const unsigned short* __restrict__ vtg,
                                                const unsigned short* __restrict__ qp,
                                                const unsigned short* __restrict__ kp,
                                                const unsigned short* __restrict__ vtp,
                                                unsigned short* __restrict__ cat) {
  __shared__ unsigned short lK[3][64 * 64];   // [tok][d] swizzled, 24KB
  __shared__ unsigned short lV[3][64 * 64];   // [d][tok] swizzled, 24KB
  __shared__ unsigned short lP[8][16 * 64];   // per-wave [q16][tok64] swizzled, 16KB

  const int tid = threadIdx.x, lane = tid & 63, wv = tid >> 6;   // 8 waves
  const int l15 = lane & 15, lg = lane >> 4;

  const int bid = blockIdx.x;
  const int w = (bid & 7) * 536 + (bid >> 3);    // XCD-contiguous chunks (4288 = 8*536)
  int qt, sidx;
  const unsigned short *Kb, *Vb, *Qb;
  unsigned short* Ob;
  long qstr, ostr;
  int nq;
  if (w < 2240) {                     // grid attention: 320 seq-heads x 7 q-tiles
    sidx = w / 7; qt = w - sidx * 7;
    Kb = kg + (long)sidx * 51200;
    Vb = vtg + (long)sidx * 51200;
    Qb = qg + (long)sidx * 51200; qstr = 64;
    int b = sidx / 20, rem = sidx % 20, ww = rem >> 2, h = rem & 3;
    Ob = cat + ((long)b * 4000 + ww) * 512 + h * 64; ostr = 2560;
    nq = 800;
  } else {                            // pool attention: 64 seq-heads x 32 q-tiles
    int w2 = w - 2240;
    sidx = w2 >> 5; qt = w2 & 31;
    Kb = kp + (long)sidx * 51200;
    Vb = vtp + (long)sidx * 51200;
    int b = sidx >> 2, h = sidx & 3;
    Qb = qp + (long)b * 4000 * 256 + h * 64; qstr = 256;
    Ob = cat + (long)b * 4000 * 512 + 256 + h * 64; ostr = 512;
    nq = 4000;
  }

  int qrow = qt * 128 + wv * 16 + l15;
  int qrc = min(qrow, nq - 1);
  short8 q0 = *(const short8*)(Qb + (long)qrc * qstr + lg * 8);
  short8 q1 = *(const short8*)(Qb + (long)qrc * qstr + 32 + lg * 8);

  float ls = 0.f;                 // sum of exp2(S) (no max subtraction: |S| bounded)
  f32x4 oacc[4] = {};

  // staging: each wave stages 8 K-rows (1KB) + 8 V^T-rows (1KB): 2 gloads/wave/tile
  const int srl = lane >> 3;                        // 0..7 (row within wave chunk)
  const int swb = (((lane & 7) ^ srl) << 4);        // pre-swizzled 16B block in 128B row

  // CLAMP only needed for tile 12 (rows/cols past 800)
#define FSTAGE(buf, t, CLAMP)                                                   \
  {                                                                             \
    int base = (t) * 64;                                                        \
    int krow = base + wv * 8 + srl;                                             \
    int vcol = base + (swb >> 1);                                               \
    if (CLAMP) { krow = min(krow, 799); vcol = min(vcol, 792); }                \
    gload16(Kb + (long)krow * 64 + (swb >> 1), &lK[buf][wv * 512]);             \
    gload16(Vb + (long)(wv * 8 + srl) * 800 + vcol, &lV[buf][wv * 512]);        \
  }

  // full (unmasked) tile
#define FTILE(buf)                                                              \
  {                                                                             \
    f32x4 st[4];                                                                \
    __builtin_amdgcn_s_setprio(1);                                              \
    _Pragma("unroll")                                                           \
    for (int ns = 0; ns < 4; ++ns) {                                            \
      int row = ns * 16 + l15;                                                  \
      short8 k0 = *(const short8*)((char*)lK[buf] + row * 128 +                 \
                                   ((lg * 16) ^ ((l15 & 7) << 4)));             \
      short8 k1 = *(const short8*)((char*)lK[buf] + row * 128 +                 \
                                   ((64 + lg * 16) ^ ((l15 & 7) << 4)));        \
      f32x4 z = {};                                                             \
      z = MFMA16(k0, q0, z);                                                    \
      z = MFMA16(k1, q1, z);                                                    \
      st[ns] = z;                                                               \
    }                                                                           \
    __builtin_amdgcn_s_setprio(0);                                              \
    float pv[16];                                                               \
    float lsl = 0.f;                                                            \
    _Pragma("unroll")                                                           \
    for (int ns = 0; ns < 4; ++ns)                                              \
      _Pragma("unroll")                                                         \
      for (int r = 0; r < 4; ++r) {                                             \
        float e = vexp2(st[ns][r]);                                             \
        pv[ns * 4 + r] = e;                                                     \
        lsl += e;                                                               \
      }                                                                         \
    ls += lsl;                                                                  \
    _Pragma("unroll")                                                           \
    for (int ns = 0; ns < 4; ++ns) {                                            \
      uint2 val;                                                                \
      val.x = cvtpk(pv[ns * 4 + 0], pv[ns * 4 + 1]);                            \
      val.y = cvtpk(pv[ns * 4 + 2], pv[ns * 4 + 3]);                            \
      *(uint2*)((char*)(&lP[wv][0]) + l15 * 128 +                               \
                ((ns * 32 + lg * 8) ^ ((l15 & 7) << 4))) = val;                 \
    }                                                                           \
    asm volatile("" ::: "memory");                                              \
    __builtin_amdgcn_s_setprio(1);                                              \
    _Pragma("unroll")                                                           \
    for (int half = 0; half < 2; ++half) {                                      \
      short8 pf = *(const short8*)((char*)(&lP[wv][0]) + l15 * 128 +            \
                                   ((half * 64 + lg * 16) ^ ((l15 & 7) << 4))); \
      _Pragma("unroll")                                                         \
      for (int ns2 = 0; ns2 < 4; ++ns2) {                                       \
        int row = ns2 * 16 + l15;                                               \
        short8 vf = *(const short8*)((char*)lV[buf] + row * 128 +               \
                                     ((half * 64 + lg * 16) ^ ((l15 & 7) << 4))); \
        oacc[ns2] = MFMA16(vf, pf, oacc[ns2]);                                  \
      }                                                                         \
    }                                                                           \
    __builtin_amdgcn_s_setprio(0);                                              \
  }

  // one-barrier-per-tile step: wait own tile-t loads, barrier, stage t+2, compute t
#define STEP(bufc, bufn, tnext, CL)                                             \
  WAITVM(2);                                                                    \
  BARRIER();                                                                    \
  FSTAGE(bufn, tnext, CL);                                                      \
  FTILE(bufc);

  FSTAGE(0, 0, 0);
  FSTAGE(1, 1, 0);
  // tiles 0..10 stage t+2 (buffer (t+2)%3 == (t-1)%3, freed by the barrier)
  STEP(0, 2, 2, 0)     // t=0
  STEP(1, 0, 3, 0)     // t=1
  STEP(2, 1, 4, 0)     // t=2
  STEP(0, 2, 5, 0)     // t=3
  STEP(1, 0, 6, 0)     // t=4
  STEP(2, 1, 7, 0)     // t=5
  STEP(0, 2, 8, 0)     // t=6
  STEP(1, 0, 9, 0)     // t=7
  STEP(2, 1, 10, 0)    // t=8
  STEP(0, 2, 11, 0)    // t=9
  STEP(1, 0, 12, 1)    // t=10 (stage tile 12 clamped into buf 0)
  // t=11: no staging (outstanding: t11 2 + t12 2 -> wait 2)
  WAITVM(2);
  BARRIER();
  FTILE(2);
  // t=12 masked: only ns=0,1 valid (local toks < 32); buf 0
  WAITVM(0);
  BARRIER();
  {
    f32x4 st[2];
    __builtin_amdgcn_s_setprio(1);
#pragma unroll
    for (int ns = 0; ns < 2; ++ns) {
      int row = ns * 16 + l15;
      short8 k0 = *(const short8*)((char*)lK[0] + row * 128 +
                                   ((lg * 16) ^ ((l15 & 7) << 4)));
      short8 k1 = *(const short8*)((char*)lK[0] + row * 128 +
                                   ((64 + lg * 16) ^ ((l15 & 7) << 4)));
      f32x4 z = {};
      z = MFMA16(k0, q0, z);
      z = MFMA16(k1, q1, z);
      st[ns] = z;
    }
    __builtin_amdgcn_s_setprio(0);
    float pv[8];
    float lsl = 0.f;
#pragma unroll
    for (int ns = 0; ns < 2; ++ns)
#pragma unroll
      for (int r = 0; r < 4; ++r) {
        float e = vexp2(st[ns][r]);
        pv[ns * 4 + r] = e;
        lsl += e;
      }
    ls += lsl;
#pragma unroll
    for (int ns = 0; ns < 4; ++ns) {
      uint2 val;
      if (ns < 2) {
        val.x = cvtpk(pv[ns * 4 + 0], pv[ns * 4 + 1]);
        val.y = cvtpk(pv[ns * 4 + 2], pv[ns * 4 + 3]);
      } else {
        val.x = 0u; val.y = 0u;
      }
      *(uint2*)((char*)(&lP[wv][0]) + l15 * 128 +
                ((ns * 32 + lg * 8) ^ ((l15 & 7) << 4))) = val;
    }
    asm volatile("" ::: "memory");
    __builtin_amdgcn_s_setprio(1);
#pragma unroll
    for (int half = 0; half < 2; ++half) {
      short8 pf = *(const short8*)((char*)(&lP[wv][0]) + l15 * 128 +
                                   ((half * 64 + lg * 16) ^ ((l15 & 7) << 4)));
#pragma unroll
      for (int ns2 = 0; ns2 < 4; ++ns2) {
        int row = ns2 * 16 + l15;
        short8 vf = *(const short8*)((char*)lV[0] + row * 128 +
                                     ((half * 64 + lg * 16) ^ ((l15 & 7) << 4)));
        oacc[ns2] = MFMA16(vf, pf, oacc[ns2]);
      }
    }
    __builtin_amdgcn_s_setprio(0);
  }
#undef STEP
#undef FSTAGE
#undef FTILE

  // ---- finalize: row sum across lg groups, normalize ----
  ls += __shfl_xor(ls, 16);
  ls += __shfl_xor(ls, 32);
  float inv = 1.0f / ls;

  // transpose O through LDS (reuse lK[0..1] as one 16KB [128 q][64 d] swizzled tile)
  __syncthreads();
  {
    int qrl = wv * 16 + l15;
#pragma unroll
    for (int ns2 = 0; ns2 < 4; ++ns2) {
      uint2 val;
      val.x = (unsigned)f2bf(oacc[ns2][0] * inv) | ((unsigned)f2bf(oacc[ns2][1] * inv) << 16);
      val.y = (unsigned)f2bf(oacc[ns2][2] * inv) | ((unsigned)f2bf(oacc[ns2][3] * inv) << 16);
      *(uint2*)((char*)lK + qrl * 128 + ((ns2 * 32 + lg * 8) ^ ((l15 & 7) << 4))) = val;
    }
  }
  __syncthreads();
#pragma unroll
  for (int p = 0; p < 2; ++p) {
    int o = (p * 512 + tid) * 16;
    int row = o >> 7, colb = o & 127;
    int qg2 = qt * 128 + row;
    if (qg2 < nq) {
      float4 v = *(const float4*)((char*)lK + (o & ~127) + (colb ^ ((row & 7) << 4)));
      *(float4*)(Ob + (long)qg2 * ostr + (colb >> 1)) = v;
    }
  }
}

// ---------- launch ----------
extern "C" void kernel_launch(void* const* d_in, const int* in_sizes, int n_in,
                              void* d_out, int out_size, void* d_ws, size_t ws_size,
                              hipStream_t stream) {
  const float* x      = (const float*)d_in[0];
  const float* gqkv_w = (const float*)d_in[1];
  const float* gqkv_b = (const float*)d_in[2];
  const float* pq_w   = (const float*)d_in[3];
  const float* pq_b   = (const float*)d_in[4];
  const float* pkv_w  = (const float*)d_in[5];
  const float* pkv_b  = (const float*)d_in[6];
  const float* conv_w = (const float*)d_in[7];
  const float* conv_b = (const float*)d_in[8];
  const float* ln_g   = (const float*)d_in[9];
  const float* ln_b   = (const float*)d_in[10];
  const float* proj_w = (const float*)d_in[11];
  const float* proj_b = (const float*)d_in[12];

  char* ws = (char*)d_ws;
  unsigned short* xbf  = (unsigned short*)(ws + 0);           // aliased by cat
  unsigned short* cat  = xbf;
  unsigned short* qg   = (unsigned short*)(ws + 65536000);    // grid Q gathered (*SM2)
  unsigned short* kg   = (unsigned short*)(ws + 98304000);    // grid K gathered
  unsigned short* vg   = (unsigned short*)(ws + 131072000);   // grid V gathered
  unsigned short* qp   = (unsigned short*)(ws + 163840000);   // pool Q (*SM2)
  unsigned short* pr   = (unsigned short*)(ws + 196608000);   // pooled (dead -> vtg)
  float*          cvt  = (float*)        (ws + 209715200);    // conv out (dead -> vtg)
  unsigned short* vtg  = (unsigned short*)(ws + 196608000);   // grid V^T (alias pr+cvt)
  unsigned short* p2   = (unsigned short*)(ws + 235929600);   // ln+gelu (dead -> vtp)
  unsigned short* vtp  = (unsigned short*)(ws + 235929600);   // pool V^T (alias p2)
  unsigned short* kp   = (unsigned short*)(ws + 249036800);   // pool K gathered
  unsigned short* vp   = (unsigned short*)(ws + 255590400);   // pool V gathered
  unsigned short* wtg  = (unsigned short*)(ws + 262144000);   // [768][512]
  unsigned short* wtkv = (unsigned short*)(ws + 263192576);
  unsigned short* wtc  = (unsigned short*)(ws + 263716864);
  unsigned short* wtp  = (unsigned short*)(ws + 264241152);

  // prep (fused cast + pool)
  castpool<<<12800, 256, 0, stream>>>(x, xbf, pr);
  wtrans5<<<dim3(1536, 5), 256, 0, stream>>>(gqkv_w, pq_w, pkv_w, conv_w, proj_w, wtg);

  // pool branch (128^2 kernel, 400-block grids)
  gemm_bf16<<<dim3(4, 100), 256, 0, stream>>>(pr, wtc, conv_b, cvt, nullptr,
                                              12800, 512, 512, 1);
  ln_gelu<<<12800, 256, 0, stream>>>(cvt, ln_g, ln_b, p2);
  gemm_bf16<<<dim3(4, 100), 256, 0, stream>>>(p2, wtkv, pkv_b, kp, vp,
                                              12800, 512, 512, 3);

  // merged gqkv + pool-Q projection (B = wtg||wtq contiguous, N=1024)
  gemm256<<<dim3(4, 250), 512, 0, stream>>>(xbf, wtg, gqkv_b, pq_b,
                                            qg, kg, vg, qp,
                                            64000, 1024, 512, 2);

  // V transposes (pr/cvt and p2 dead by now)
  vtrans<<<dim3(13, 320), 256, 0, stream>>>(vg, vtg);
  vtrans<<<dim3(13, 64), 256, 0, stream>>>(vp, vtp);

  // merged attentions -> cat (xbf dead after merged GEMM): 2240 grid + 2048 pool
  flash_v9<<<4288, 512, 0, stream>>>(qg, kg, vtg, qp, kp, vtp, cat);

  // output projection (fp32 out)
  gemm256<<<dim3(2, 250), 512, 0, stream>>>(cat, wtp, proj_b, nullptr,
                                            d_out, nullptr, nullptr, nullptr,
                                            64000, 512, 512, 1);
}

// Round 18
// 435.493 us; speedup vs baseline: 1.0059x; 1.0059x over previous
//
#include <hip/hip_runtime.h>
#include <hip/hip_bf16.h>
#include <math.h>

// ---------- types ----------
typedef short short8 __attribute__((ext_vector_type(8)));
typedef float f32x4 __attribute__((ext_vector_type(4)));

#define MFMA16(a, b, c) __builtin_amdgcn_mfma_f32_16x16x32_bf16((a), (b), (c), 0, 0, 0)
#define SM2 0.18033688f   // 0.125 * log2(e): QK^T softmax done in exp2 domain

// raw barrier + compiler fence (counted-vmcnt pipeline: loads stay in flight across it)
#define BARRIER() { __builtin_amdgcn_sched_barrier(0); \
                    asm volatile("s_barrier" ::: "memory"); \
                    __builtin_amdgcn_sched_barrier(0); }
#define WAITVM(n) asm volatile("s_waitcnt vmcnt(" #n ")" ::: "memory")

__device__ __forceinline__ unsigned short f2bf(float f) {
  unsigned u = __builtin_bit_cast(unsigned, f);
  u += 0x7FFFu + ((u >> 16) & 1u);   // RNE
  return (unsigned short)(u >> 16);
}
__device__ __forceinline__ float b2f(unsigned short h) {
  return __builtin_bit_cast(float, (unsigned)h << 16);
}
__device__ __forceinline__ unsigned cvtpk(float lo, float hi) {
  unsigned r;
  asm("v_cvt_pk_bf16_f32 %0, %1, %2" : "=v"(r) : "v"(lo), "v"(hi));
  return r;
}
__device__ __forceinline__ float vexp2(float x) {   // single-inst 2^x (inputs bounded)
  float r;
  asm("v_exp_f32 %0, %1" : "=v"(r) : "v"(x));
  return r;
}
// async global->LDS, 16B/lane; LDS dest = wave-uniform base (+ lane*16 by HW)
__device__ __forceinline__ void gload16(const void* g, void* l) {
  __builtin_amdgcn_global_load_lds((const __attribute__((address_space(1))) unsigned*)g,
                                   (__attribute__((address_space(3))) unsigned*)l, 16, 0, 0);
}

// ---------- fused cast + pool: x fp32 -> xbf bf16 (all rows) + pr bf16 (pooled) ----------
__global__ __launch_bounds__(256) void castpool(const float* __restrict__ x,
                                                unsigned short* __restrict__ xbf,
                                                unsigned short* __restrict__ pr) {
  long bi = blockIdx.x;                 // 0..12799
  const float* src = x + bi * 2560;
  unsigned short* dst = xbf + bi * 2560;
  int c = threadIdx.x * 2;
  float ax = 0.f, ay = 0.f;
#pragma unroll
  for (int w = 0; w < 5; ++w) {
    float2 v = *(const float2*)(src + w * 512 + c);
    ax += v.x; ay += v.y;
    unsigned o = (unsigned)f2bf(v.x) | ((unsigned)f2bf(v.y) << 16);
    *(unsigned*)(dst + w * 512 + c) = o;
  }
  unsigned o = (unsigned)f2bf(ax * 0.2f) | ((unsigned)f2bf(ay * 0.2f) << 16);
  *(unsigned*)(pr + bi * 512 + c) = o;
}

// merged transpose of the 5 weight matrices [512,N] fp32 -> [N,512] bf16 (contiguous dst)
__global__ __launch_bounds__(256) void wtrans5(const float* __restrict__ w0,
                                               const float* __restrict__ w1,
                                               const float* __restrict__ w2,
                                               const float* __restrict__ w3,
                                               const float* __restrict__ w4,
                                               unsigned short* __restrict__ dst) {
  int seg = blockIdx.y;
  const float* src; int N; long doff;
  switch (seg) {
    case 0:  src = w0; N = 768; doff = 0;       break;   // gqkv -> wtg
    case 1:  src = w1; N = 256; doff = 393216;  break;   // pq   -> wtq
    case 2:  src = w2; N = 512; doff = 524288;  break;   // pkv  -> wtkv
    case 3:  src = w3; N = 512; doff = 786432;  break;   // conv -> wtc
    default: src = w4; N = 512; doff = 1048576; break;   // proj -> wtp
  }
  int idx = blockIdx.x * 256 + threadIdx.x;
  if (idx < 512 * N) {
    int k = idx / N, n = idx - k * N;
    dst[doff + (long)n * 512 + k] = f2bf(src[idx]);
  }
}

// LayerNorm (eps 1e-5, biased var) + erf-GELU ; fp32 [rows,512] -> bf16
__global__ __launch_bounds__(256) void ln_gelu(const float* __restrict__ in,
                                               const float* __restrict__ g,
                                               const float* __restrict__ be,
                                               unsigned short* __restrict__ out) {
  long row = blockIdx.x;
  const float* src = in + row * 512;
  int tid = threadIdx.x;
  float2 v = *(const float2*)(src + tid * 2);
  float s = v.x + v.y, sq = v.x * v.x + v.y * v.y;
#pragma unroll
  for (int m = 1; m < 64; m <<= 1) {
    s  += __shfl_xor(s, m);
    sq += __shfl_xor(sq, m);
  }
  __shared__ float ss[4], ssq[4];
  int wv = tid >> 6;
  if ((tid & 63) == 0) { ss[wv] = s; ssq[wv] = sq; }
  __syncthreads();
  s  = ss[0] + ss[1] + ss[2] + ss[3];
  sq = ssq[0] + ssq[1] + ssq[2] + ssq[3];
  float mu = s * (1.0f / 512.0f);
  float var = sq * (1.0f / 512.0f) - mu * mu;
  float rs = rsqrtf(var + 1e-5f);
  int c = tid * 2;
#pragma unroll
  for (int e = 0; e < 2; ++e) {
    float xv = (e == 0 ? v.x : v.y);
    float y = (xv - mu) * rs * g[c + e] + be[c + e];
    float ge = 0.5f * y * (1.0f + erff(y * 0.70710678118654752f));
    out[row * 512 + c + e] = f2bf(ge);
  }
}

// ---------- V transpose: src [seq][800][64] -> dst [seq][64][800] ----------
__global__ __launch_bounds__(256) void vtrans(const unsigned short* __restrict__ src,
                                              unsigned short* __restrict__ dst) {
  __shared__ unsigned short tile[64][64];
  int jt = blockIdx.x, s = blockIdx.y;
  int tid = threadIdx.x;
#pragma unroll
  for (int p = 0; p < 2; ++p) {
    int idx = p * 256 + tid;
    int j = idx >> 3, d8 = (idx & 7) * 8;
    int jg = min(jt * 64 + j, 799);
    short8 v = *(const short8*)(src + ((long)s * 800 + jg) * 64 + d8);
    *(short8*)&tile[j][d8] = v;
  }
  __syncthreads();
  int d = tid >> 2, jseg = (tid & 3) * 16;
  if (jt * 64 + jseg < 800) {
    short8 h0, h1;
#pragma unroll
    for (int i = 0; i < 8; ++i) { h0[i] = (short)tile[jseg + i][d]; h1[i] = (short)tile[jseg + 8 + i][d]; }
    unsigned short* o = dst + ((long)s * 64 + d) * 800 + jt * 64 + jseg;
    *(short8*)o = h0;
    *(short8*)(o + 8) = h1;
  }
}

// ---------- small GEMM (pool branch): 128x128 tile, 4 waves, BK=32 ----------
// gmode 1: fp32 out0 [M][N];  gmode 3: kv-split gathered K/V [64][800][64]
__global__ __launch_bounds__(256) void gemm_bf16(const unsigned short* __restrict__ A,
                                                 const unsigned short* __restrict__ Bt,
                                                 const float* __restrict__ bias,
                                                 void* __restrict__ out0, void* __restrict__ out1,
                                                 int M, int N, int K, int gmode) {
  __shared__ unsigned short lA[2][128 * 32];
  __shared__ unsigned short lB[2][128 * 32];
  const int tid = threadIdx.x;
  const int lane = tid & 63, wv = tid >> 6;
  const int wr = wv >> 1, wc = wv & 1;
  const int l15 = lane & 15, lg = lane >> 4;

  const int nwg = gridDim.x * gridDim.y;
  const int bid = blockIdx.y * gridDim.x + blockIdx.x;
  const int w = (bid & 7) * (nwg >> 3) + (bid >> 3);
  const int m0 = (w / gridDim.x) * 128, n0 = (w % gridDim.x) * 128;

  const int r0  = tid >> 2;
  const int sw0 = ((tid & 3) * 16) ^ ((r0 & 3) << 4);
  const unsigned short* As0 = A  + (size_t)(m0 + r0)      * K + (sw0 >> 1);
  const unsigned short* As1 = A  + (size_t)(m0 + 64 + r0) * K + (sw0 >> 1);
  const unsigned short* Bs0 = Bt + (size_t)(n0 + r0)      * K + (sw0 >> 1);
  const unsigned short* Bs1 = Bt + (size_t)(n0 + 64 + r0) * K + (sw0 >> 1);

  f32x4 acc[4][4] = {};

#define GSTAGE(buf, k0)                                   \
  {                                                       \
    gload16(As0 + (k0), &lA[buf][wv * 512]);              \
    gload16(As1 + (k0), &lA[buf][2048 + wv * 512]);       \
    gload16(Bs0 + (k0), &lB[buf][wv * 512]);              \
    gload16(Bs1 + (k0), &lB[buf][2048 + wv * 512]);       \
  }

  const int nt = K >> 5;
  GSTAGE(0, 0);
  if (nt > 1) GSTAGE(1, 32);
  for (int t = 0; t < nt; ++t) {
    if (t + 1 < nt) { WAITVM(4); } else { WAITVM(0); }
    BARRIER();
    short8 af[4], bfr[4];
#pragma unroll
    for (int s2 = 0; s2 < 4; ++s2) {
      int ra = wr * 64 + s2 * 16 + l15;
      int rb = wc * 64 + s2 * 16 + l15;
      af[s2]  = *(const short8*)((char*)lA[t & 1] + ra * 64 + ((lg * 16) ^ ((ra & 3) << 4)));
      bfr[s2] = *(const short8*)((char*)lB[t & 1] + rb * 64 + ((lg * 16) ^ ((rb & 3) << 4)));
    }
#pragma unroll
    for (int i = 0; i < 4; ++i)
#pragma unroll
      for (int j = 0; j < 4; ++j)
        acc[i][j] = MFMA16(af[i], bfr[j], acc[i][j]);
    BARRIER();
    if (t + 2 < nt) GSTAGE(t & 1, (t + 2) * 32);
  }
#undef GSTAGE

#pragma unroll
  for (int i = 0; i < 4; ++i) {
#pragma unroll
    for (int r = 0; r < 4; ++r) {
      int row = m0 + wr * 64 + i * 16 + lg * 4 + r;
      long rg = 0;
      if (gmode == 3) {
        int b = row / 800, jj = row - b * 800;
        rg = (long)b * 204800 + (long)jj * 64;
      }
#pragma unroll
      for (int j = 0; j < 4; ++j) {
        int col = n0 + wc * 64 + j * 16 + l15;
        float vv = acc[i][j][r] + bias[col];
        if (gmode == 1) {
          ((float*)out0)[(size_t)row * N + col] = vv;
        } else {  // gmode 3
          int hh = (col >> 6) & 3, d = col & 63;
          unsigned short* dst = (col < 256) ? (unsigned short*)out0 : (unsigned short*)out1;
          dst[rg + hh * 51200 + d] = f2bf(vv);
        }
      }
    }
  }
}

// ---------- big GEMM: 256x256 tile, 8 waves (2Mx4N), wave-tile 128x64, BK=64 ----------
// 4-phase-per-K-tile schedule; coalesced LDS epilogue (R11, proven).
__global__ __launch_bounds__(512, 2) void gemm256(const unsigned short* __restrict__ A,
                                                  const unsigned short* __restrict__ Bt,
                                                  const float* __restrict__ bias,
                                                  const float* __restrict__ bias2,
                                                  void* __restrict__ out0, void* __restrict__ out1,
                                                  void* __restrict__ out2, void* __restrict__ out3,
                                                  int M, int N, int K, int gmode) {
  __shared__ char lds[131072];                 // lA[buf]=lds+buf*32768; lB[buf]=lds+65536+buf*32768
  const int tid = threadIdx.x;
  const int lane = tid & 63, wv = tid >> 6;    // 8 waves
  const int wr = wv >> 2, wc = wv & 3;         // 2M x 4N
  const int l15 = lane & 15, lg = lane >> 4;

  // bijective XCD swizzle (m204)
  const int nwg = gridDim.x * gridDim.y;
  const int bid = blockIdx.y * gridDim.x + blockIdx.x;
  const int q = nwg >> 3, r8 = nwg & 7;
  const int xcd = bid & 7, idx = bid >> 3;
  const int w = (xcd < r8 ? xcd * (q + 1) : r8 * (q + 1) + (xcd - r8) * q) + idx;
  const int m0 = (w / gridDim.x) * 256, n0 = (w % gridDim.x) * 256;

  const int srow = tid >> 3;                                        // 0..63
  const int scol = ((((lane & 7) ^ (lane >> 3)) << 4)) >> 1;        // element offset
  const unsigned short* Ag[4];
  const unsigned short* Bg[4];
#pragma unroll
  for (int g = 0; g < 4; ++g) {
    Ag[g] = A  + (size_t)(m0 + g * 64 + srow) * K + scol;
    Bg[g] = Bt + (size_t)(n0 + g * 64 + srow) * K + scol;
  }

  f32x4 acc[8][4] = {};

#define GSTAGE2(buf, k0)                                                    \
  {                                                                         \
    _Pragma("unroll")                                                       \
    for (int g = 0; g < 4; ++g)                                             \
      gload16(Ag[g] + (k0), lds + (buf) * 32768 + g * 8192 + wv * 1024);    \
    _Pragma("unroll")                                                       \
    for (int g = 0; g < 4; ++g)                                             \
      gload16(Bg[g] + (k0), lds + 65536 + (buf) * 32768 + g * 8192 + wv * 1024); \
  }
#define RDA4(ibase, kk)                                             \
  _Pragma("unroll")                                                 \
  for (int i = 0; i < 4; ++i) {                                     \
    int ra = wr * 128 + ((ibase) + i) * 16 + l15;                   \
    af[i] = *(const short8*)(bufA + ra * 128 +                      \
             (((kk) * 64 + lg * 16) ^ ((ra & 7) << 4)));            \
  }
#define RDB4(kk)                                                    \
  _Pragma("unroll")                                                 \
  for (int j = 0; j < 4; ++j) {                                     \
    int rb = wc * 64 + j * 16 + l15;                                \
    bf[j] = *(const short8*)(bufB + rb * 128 +                      \
             (((kk) * 64 + lg * 16) ^ ((rb & 7) << 4)));            \
  }
#define PH_MFMA(ibase)                                              \
  __builtin_amdgcn_s_setprio(1);                                    \
  _Pragma("unroll")                                                 \
  for (int i = 0; i < 4; ++i)                                       \
    _Pragma("unroll")                                               \
    for (int j = 0; j < 4; ++j)                                     \
      acc[(ibase) + i][j] = MFMA16(af[i], bf[j], acc[(ibase) + i][j]); \
  __builtin_amdgcn_s_setprio(0);

  const int nt = K >> 6;                       // BK=64
  GSTAGE2(0, 0);
  if (nt > 1) GSTAGE2(1, 64);
  for (int t = 0; t < nt; ++t) {
    if (t + 1 < nt) { WAITVM(8); } else { WAITVM(0); }
    BARRIER();
    const char* bufA = lds + (t & 1) * 32768;
    const char* bufB = lds + 65536 + (t & 1) * 32768;
    short8 af[4], bf[4];
    RDA4(0, 0); RDB4(0);
    BARRIER();
    PH_MFMA(0);
    BARRIER();
    RDA4(4, 0);
    BARRIER();
    PH_MFMA(4);
    BARRIER();
    RDA4(0, 1); RDB4(1);
    BARRIER();
    PH_MFMA(0);
    BARRIER();
    RDA4(4, 1);
    BARRIER();
    PH_MFMA(4);
    BARRIER();
    if (t + 2 < nt) GSTAGE2(t & 1, (t + 2) * 64);
  }
#undef GSTAGE2
#undef RDA4
#undef RDB4
#undef PH_MFMA

  // ---- coalesced epilogue via LDS (8 slices of [32 rows][256 cols]) ----
  float bb[4];
#pragma unroll
  for (int j = 0; j < 4; ++j) {
    int col = n0 + wc * 64 + j * 16 + l15;
    bb[j] = (gmode == 2 && col >= 768) ? bias2[col - 768] : bias[col];
  }
  const float qsc = (gmode == 2 && (n0 == 0 || n0 == 768)) ? SM2 : 1.0f;
  const int lwr = wr * 16 + lg * 4;
  const int lcol = wc * 64 + l15;
  const int lr_t = tid >> 4;
  const int c16 = (tid & 15) * 16;
  const int wrg = lr_t >> 4, rl = lr_t & 15;

  if (gmode == 1) {
    float* ls4 = (float*)lds;                  // [32][260] padded
#pragma unroll
    for (int i = 0; i < 8; ++i) {
      __syncthreads();
#pragma unroll
      for (int j = 0; j < 4; ++j)
#pragma unroll
        for (int rr = 0; rr < 4; ++rr)
          ls4[(lwr + rr) * 260 + lcol + j * 16] = acc[i][j][rr] + bb[j];
      __syncthreads();
      int gr = m0 + wrg * 128 + i * 16 + rl;
      float* dst = (float*)out0 + (size_t)gr * N + n0 + c16;
      const float* src = &ls4[lr_t * 260 + c16];
#pragma unroll
      for (int e = 0; e < 4; ++e)
        *(float4*)(dst + e * 4) = *(const float4*)(src + e * 4);
    }
  } else {  // gmode 2: merged qkv+poolq, bf16 gathered outputs
    unsigned short* ls2 = (unsigned short*)lds; // [32][264] padded
#pragma unroll
    for (int i = 0; i < 8; ++i) {
      __syncthreads();
#pragma unroll
      for (int j = 0; j < 4; ++j)
#pragma unroll
        for (int rr = 0; rr < 4; ++rr)
          ls2[(lwr + rr) * 264 + lcol + j * 16] = f2bf((acc[i][j][rr] + bb[j]) * qsc);
      __syncthreads();
      int gr = m0 + wrg * 128 + i * 16 + rl;
      unsigned short* dst;
      if (n0 == 768) {                         // pool Q: [row][256]
        dst = (unsigned short*)out3 + (size_t)gr * 256 + c16;
      } else {                                 // grid Q/K/V gathered [320][800][64]
        int b = gr / 4000, l = gr - b * 4000;
        int jj = l / 5, ww = l - jj * 5;
        long rg = (long)(b * 5 + ww) * 204800 + (long)jj * 64;
        unsigned short* base = (n0 == 0) ? (unsigned short*)out0
                             : (n0 == 256) ? (unsigned short*)out1 : (unsigned short*)out2;
        dst = base + rg + (c16 >> 6) * 51200 + (c16 & 63);
      }
      const unsigned short* src = &ls2[lr_t * 264 + c16];
      *(uint4*)dst = *(const uint4*)src;
      *(uint4*)(dst + 8) = *(const uint4*)(src + 8);
    }
  }
}

// ---------- flash attention v7: no-max softmax (bounded scores), static buffers ----------
// grid: 2240 grid-attn blocks then 2048 pool blocks. 4288 total, 8 waves, QBLK=128.
__global__ __launch_bounds__(512) void flash_v7(const unsigned short* __restrict__ qg,
                                                const unsigned short* __restrict__ kg,
                                                const unsigned short* __restrict__ vtg,
                                                const unsigned short* __restrict__ qp,
                                                const unsigned short* __restrict__ kp,
                                                const unsigned short* __restrict__ vtp,
                                                unsigned short* __restrict__ cat) {
  __shared__ unsigned short lK[2][64 * 64];   // [tok][d] swizzled, 16KB
  __shared__ unsigned short lV[2][64 * 64];   // [d][tok] swizzled, 16KB
  __shared__ unsigned short lP[8][16 * 64];   // per-wave [q16][tok64] swizzled, 16KB

  const int tid = threadIdx.x, lane = tid & 63, wv = tid >> 6;   // 8 waves
  const int l15 = lane & 15, lg = lane >> 4;

  const int bid = blockIdx.x;
  const int w = (bid & 7) * 536 + (bid >> 3);    // XCD-contiguous chunks (4288 = 8*536)
  int qt, sidx;
  const unsigned short *Kb, *Vb, *Qb;
  unsigned short* Ob;
  long qstr, ostr;
  int nq;
  if (w < 2240) {                     // grid attention: 320 seq-heads x 7 q-tiles
    sidx = w / 7; qt = w - sidx * 7;
    Kb = kg + (long)sidx * 51200;
    Vb = vtg + (long)sidx * 51200;
    Qb = qg + (long)sidx * 51200; qstr = 64;
    int b = sidx / 20, rem = sidx % 20, ww = rem >> 2, h = rem & 3;
    Ob = cat + ((long)b * 4000 + ww) * 512 + h * 64; ostr = 2560;
    nq = 800;
  } else {                            // pool attention: 64 seq-heads x 32 q-tiles
    int w2 = w - 2240;
    sidx = w2 >> 5; qt = w2 & 31;
    Kb = kp + (long)sidx * 51200;
    Vb = vtp + (long)sidx * 51200;
    int b = sidx >> 2, h = sidx & 3;
    Qb = qp + (long)b * 4000 * 256 + h * 64; qstr = 256;
    Ob = cat + (long)b * 4000 * 512 + 256 + h * 64; ostr = 512;
    nq = 4000;
  }

  int qrow = qt * 128 + wv * 16 + l15;
  int qrc = min(qrow, nq - 1);
  short8 q0 = *(const short8*)(Qb + (long)qrc * qstr + lg * 8);
  short8 q1 = *(const short8*)(Qb + (long)qrc * qstr + 32 + lg * 8);

  float ls = 0.f;                 // sum of exp2(S) (no max subtraction: |S| bounded)
  f32x4 oacc[4] = {};

  // staging: each wave stages 8 K-rows (1KB) + 8 V^T-rows (1KB): 2 gloads/wave/tile
  const int srl = lane >> 3;                        // 0..7 (row within wave chunk)
  const int swb = (((lane & 7) ^ srl) << 4);        // pre-swizzled 16B block in 128B row

  // CLAMP only needed for tile 12 (rows/cols past 800)
#define FSTAGE(buf, t, CLAMP)                                                   \
  {                                                                             \
    int base = (t) * 64;                                                        \
    int krow = base + wv * 8 + srl;                                             \
    int vcol = base + (swb >> 1);                                               \
    if (CLAMP) { krow = min(krow, 799); vcol = min(vcol, 792); }                \
    gload16(Kb + (long)krow * 64 + (swb >> 1), &lK[buf][wv * 512]);             \
    gload16(Vb + (long)(wv * 8 + srl) * 800 + vcol, &lV[buf][wv * 512]);        \
  }

  // full (unmasked) tile
#define FTILE(buf)                                                              \
  {                                                                             \
    f32x4 st[4];                                                                \
    __builtin_amdgcn_s_setprio(1);                                              \
    _Pragma("unroll")                                                           \
    for (int ns = 0; ns < 4; ++ns) {                                            \
      int row = ns * 16 + l15;                                                  \
      short8 k0 = *(const short8*)((char*)lK[buf] + row * 128 +                 \
                                   ((lg * 16) ^ ((l15 & 7) << 4)));             \
      short8 k1 = *(const short8*)((char*)lK[buf] + row * 128 +                 \
                                   ((64 + lg * 16) ^ ((l15 & 7) << 4)));        \
      f32x4 z = {};                                                             \
      z = MFMA16(k0, q0, z);                                                    \
      z = MFMA16(k1, q1, z);                                                    \
      st[ns] = z;                                                               \
    }                                                                           \
    __builtin_amdgcn_s_setprio(0);                                              \
    float pv[16];                                                               \
    float lsl = 0.f;                                                            \
    _Pragma("unroll")                                                           \
    for (int ns = 0; ns < 4; ++ns)                                              \
      _Pragma("unroll")                                                         \
      for (int r = 0; r < 4; ++r) {                                             \
        float e = vexp2(st[ns][r]);                                             \
        pv[ns * 4 + r] = e;                                                     \
        lsl += e;                                                               \
      }                                                                         \
    ls += lsl;                                                                  \
    _Pragma("unroll")                                                           \
    for (int ns = 0; ns < 4; ++ns) {                                            \
      uint2 val;                                                                \
      val.x = cvtpk(pv[ns * 4 + 0], pv[ns * 4 + 1]);                            \
      val.y = cvtpk(pv[ns * 4 + 2], pv[ns * 4 + 3]);                            \
      *(uint2*)((char*)(&lP[wv][0]) + l15 * 128 +                               \
                ((ns * 32 + lg * 8) ^ ((l15 & 7) << 4))) = val;                 \
    }                                                                           \
    asm volatile("" ::: "memory");                                              \
    __builtin_amdgcn_s_setprio(1);                                              \
    _Pragma("unroll")                                                           \
    for (int half = 0; half < 2; ++half) {                                      \
      short8 pf = *(const short8*)((char*)(&lP[wv][0]) + l15 * 128 +            \
                                   ((half * 64 + lg * 16) ^ ((l15 & 7) << 4))); \
      _Pragma("unroll")                                                         \
      for (int ns2 = 0; ns2 < 4; ++ns2) {                                       \
        int row = ns2 * 16 + l15;                                               \
        short8 vf = *(const short8*)((char*)lV[buf] + row * 128 +               \
                                     ((half * 64 + lg * 16) ^ ((l15 & 7) << 4))); \
        oacc[ns2] = MFMA16(vf, pf, oacc[ns2]);                                  \
      }                                                                         \
    }                                                                           \
    __builtin_amdgcn_s_setprio(0);                                              \
  }

  // tiles 0..11 full; tile 12 has only local toks 0..31 (ns=0,1) -> static mask
  FSTAGE(0, 0, 0);
  FSTAGE(1, 1, 0);
  for (int tb = 0; tb < 10; tb += 2) {
    WAITVM(2); BARRIER();
    FTILE(0);
    BARRIER();
    FSTAGE(0, tb + 2, 0);
    WAITVM(2); BARRIER();
    FTILE(1);
    BARRIER();
    FSTAGE(1, tb + 3, 0);
  }
  // tb = 10: tile 10, then stage clamped tile 12; tile 11; tile 12 masked
  WAITVM(2); BARRIER();
  FTILE(0);
  BARRIER();
  FSTAGE(0, 12, 1);
  WAITVM(2); BARRIER();
  FTILE(1);
  BARRIER();
  WAITVM(0); BARRIER();
  {   // masked tile 12: only ns=0,1 valid (local toks < 32)
    f32x4 st[2];
    __builtin_amdgcn_s_setprio(1);
#pragma unroll
    for (int ns = 0; ns < 2; ++ns) {
      int row = ns * 16 + l15;
      short8 k0 = *(const short8*)((char*)lK[0] + row * 128 +
                                   ((lg * 16) ^ ((l15 & 7) << 4)));
      short8 k1 = *(const short8*)((char*)lK[0] + row * 128 +
                                   ((64 + lg * 16) ^ ((l15 & 7) << 4)));
      f32x4 z = {};
      z = MFMA16(k0, q0, z);
      z = MFMA16(k1, q1, z);
      st[ns] = z;
    }
    __builtin_amdgcn_s_setprio(0);
    float pv[8];
    float lsl = 0.f;
#pragma unroll
    for (int ns = 0; ns < 2; ++ns)
#pragma unroll
      for (int r = 0; r < 4; ++r) {
        float e = vexp2(st[ns][r]);
        pv[ns * 4 + r] = e;
        lsl += e;
      }
    ls += lsl;
#pragma unroll
    for (int ns = 0; ns < 4; ++ns) {
      uint2 val;
      if (ns < 2) {
        val.x = cvtpk(pv[ns * 4 + 0], pv[ns * 4 + 1]);
        val.y = cvtpk(pv[ns * 4 + 2], pv[ns * 4 + 3]);
      } else {
        val.x = 0u; val.y = 0u;
      }
      *(uint2*)((char*)(&lP[wv][0]) + l15 * 128 +
                ((ns * 32 + lg * 8) ^ ((l15 & 7) << 4))) = val;
    }
    asm volatile("" ::: "memory");
    __builtin_amdgcn_s_setprio(1);
#pragma unroll
    for (int half = 0; half < 2; ++half) {
      short8 pf = *(const short8*)((char*)(&lP[wv][0]) + l15 * 128 +
                                   ((half * 64 + lg * 16) ^ ((l15 & 7) << 4)));
#pragma unroll
      for (int ns2 = 0; ns2 < 4; ++ns2) {
        int row = ns2 * 16 + l15;
        short8 vf = *(const short8*)((char*)lV[0] + row * 128 +
                                     ((half * 64 + lg * 16) ^ ((l15 & 7) << 4)));
        oacc[ns2] = MFMA16(vf, pf, oacc[ns2]);
      }
    }
    __builtin_amdgcn_s_setprio(0);
  }
#undef FSTAGE
#undef FTILE

  // ---- finalize: row sum across lg groups, normalize ----
  ls += __shfl_xor(ls, 16);
  ls += __shfl_xor(ls, 32);
  float inv = 1.0f / ls;

  // transpose O through LDS (reuse lK[0..1] as one 16KB [128 q][64 d] swizzled tile)
  __syncthreads();
  {
    int qrl = wv * 16 + l15;
#pragma unroll
    for (int ns2 = 0; ns2 < 4; ++ns2) {
      uint2 val;
      val.x = (unsigned)f2bf(oacc[ns2][0] * inv) | ((unsigned)f2bf(oacc[ns2][1] * inv) << 16);
      val.y = (unsigned)f2bf(oacc[ns2][2] * inv) | ((unsigned)f2bf(oacc[ns2][3] * inv) << 16);
      *(uint2*)((char*)lK + qrl * 128 + ((ns2 * 32 + lg * 8) ^ ((l15 & 7) << 4))) = val;
    }
  }
  __syncthreads();
#pragma unroll
  for (int p = 0; p < 2; ++p) {
    int o = (p * 512 + tid) * 16;
    int row = o >> 7, colb = o & 127;
    int qg2 = qt * 128 + row;
    if (qg2 < nq) {
      float4 v = *(const float4*)((char*)lK + (o & ~127) + (colb ^ ((row & 7) << 4)));
      *(float4*)(Ob + (long)qg2 * ostr + (colb >> 1)) = v;
    }
  }
}

// ---------- launch ----------
extern "C" void kernel_launch(void* const* d_in, const int* in_sizes, int n_in,
                              void* d_out, int out_size, void* d_ws, size_t ws_size,
                              hipStream_t stream) {
  const float* x      = (const float*)d_in[0];
  const float* gqkv_w = (const float*)d_in[1];
  const float* gqkv_b = (const float*)d_in[2];
  const float* pq_w   = (const float*)d_in[3];
  const float* pq_b   = (const float*)d_in[4];
  const float* pkv_w  = (const float*)d_in[5];
  const float* pkv_b  = (const float*)d_in[6];
  const float* conv_w = (const float*)d_in[7];
  const float* conv_b = (const float*)d_in[8];
  const float* ln_g   = (const float*)d_in[9];
  const float* ln_b   = (const float*)d_in[10];
  const float* proj_w = (const float*)d_in[11];
  const float* proj_b = (const float*)d_in[12];

  char* ws = (char*)d_ws;
  unsigned short* xbf  = (unsigned short*)(ws + 0);           // aliased by cat
  unsigned short* cat  = xbf;
  unsigned short* qg   = (unsigned short*)(ws + 65536000);    // grid Q gathered (*SM2)
  unsigned short* kg   = (unsigned short*)(ws + 98304000);    // grid K gathered
  unsigned short* vg   = (unsigned short*)(ws + 131072000);   // grid V gathered
  unsigned short* qp   = (unsigned short*)(ws + 163840000);   // pool Q (*SM2)
  unsigned short* pr   = (unsigned short*)(ws + 196608000);   // pooled (dead -> vtg)
  float*          cvt  = (float*)        (ws + 209715200);    // conv out (dead -> vtg)
  unsigned short* vtg  = (unsigned short*)(ws + 196608000);   // grid V^T (alias pr+cvt)
  unsigned short* p2   = (unsigned short*)(ws + 235929600);   // ln+gelu (dead -> vtp)
  unsigned short* vtp  = (unsigned short*)(ws + 235929600);   // pool V^T (alias p2)
  unsigned short* kp   = (unsigned short*)(ws + 249036800);   // pool K gathered
  unsigned short* vp   = (unsigned short*)(ws + 255590400);   // pool V gathered
  unsigned short* wtg  = (unsigned short*)(ws + 262144000);   // [768][512]
  unsigned short* wtkv = (unsigned short*)(ws + 263192576);
  unsigned short* wtc  = (unsigned short*)(ws + 263716864);
  unsigned short* wtp  = (unsigned short*)(ws + 264241152);

  // prep (fused cast + pool)
  castpool<<<12800, 256, 0, stream>>>(x, xbf, pr);
  wtrans5<<<dim3(1536, 5), 256, 0, stream>>>(gqkv_w, pq_w, pkv_w, conv_w, proj_w, wtg);

  // pool branch (128^2 kernel, 400-block grids)
  gemm_bf16<<<dim3(4, 100), 256, 0, stream>>>(pr, wtc, conv_b, cvt, nullptr,
                                              12800, 512, 512, 1);
  ln_gelu<<<12800, 256, 0, stream>>>(cvt, ln_g, ln_b, p2);
  gemm_bf16<<<dim3(4, 100), 256, 0, stream>>>(p2, wtkv, pkv_b, kp, vp,
                                              12800, 512, 512, 3);

  // merged gqkv + pool-Q projection (B = wtg||wtq contiguous, N=1024)
  gemm256<<<dim3(4, 250), 512, 0, stream>>>(xbf, wtg, gqkv_b, pq_b,
                                            qg, kg, vg, qp,
                                            64000, 1024, 512, 2);

  // V transposes (pr/cvt and p2 dead by now)
  vtrans<<<dim3(13, 320), 256, 0, stream>>>(vg, vtg);
  vtrans<<<dim3(13, 64), 256, 0, stream>>>(vp, vtp);

  // merged attentions -> cat (xbf dead after merged GEMM): 2240 grid + 2048 pool
  flash_v7<<<4288, 512, 0, stream>>>(qg, kg, vtg, qp, kp, vtp, cat);

  // output projection (fp32 out)
  gemm256<<<dim3(2, 250), 512, 0, stream>>>(cat, wtp, proj_b, nullptr,
                                            d_out, nullptr, nullptr, nullptr,
                                            64000, 512, 512, 1);
}